// Round 15
// baseline (1167.970 us; speedup 1.0000x reference)
//
#include <hip/hip_runtime.h>
#include <math.h>

constexpr int HD  = 128;     // hidden
constexpr int FNN = 6;       // node in-features
constexpr int FEE = 3;       // edge in-features
constexpr int NN  = 40000;   // nodes per chunk
constexpr int EE  = 240000;  // edges
constexpr int SS  = 4;       // mp steps
constexpr size_t NHD = (size_t)NN*HD;
constexpr size_t EHD = (size_t)EE*HD;

typedef __bf16 bf16_t;
typedef bf16_t bf16x8 __attribute__((ext_vector_type(8)));
typedef float  f32x4  __attribute__((ext_vector_type(4)));

__device__ __forceinline__ f32x4 mfma16(bf16x8 a, bf16x8 b, f32x4 c){
  return __builtin_amdgcn_mfma_f32_16x16x32_bf16(a, b, c, 0, 0, 0);
}
__device__ __forceinline__ float elu(float v){ return v > 0.f ? v : __expf(v) - 1.f; }

// ---------------------------------------------------------------- weight pack
struct PackJob { const float* src; int K; };
struct PackArgs { PackJob j[30]; };

__global__ void __launch_bounds__(256) k_pack(PackArgs pa, bf16_t* __restrict__ dst){
  int gid = blockIdx.x*256 + threadIdx.x;
  int base = 0;
  #pragma unroll 1
  for (int i = 0; i < 30; ++i){
    int Kp = (pa.j[i].K + 31) & ~31;
    int sz = Kp * HD;
    if (gid < base + sz){
      int idx = gid - base;
      int jj = idx & 7, c = (idx >> 3) & 127, G = idx >> 10;
      int k = G*8 + jj;
      float v = (k < pa.j[i].K) ? pa.j[i].src[(size_t)k*HD + c] : 0.f;
      dst[base + idx] = (bf16_t)v;
      return;
    }
    base += sz;
  }
}

// ---------------------------------------------------------------- CSR build
__global__ void k_cnt(const int* __restrict__ ei1, int* __restrict__ cnt){
  int t = blockIdx.x*blockDim.x + threadIdx.x;
  if (t < EE) atomicAdd(cnt + ei1[t], 1);
}

__global__ void __launch_bounds__(1024) k_scanA(const int* __restrict__ cnt,
    int* __restrict__ incl, int* __restrict__ bsum){
  __shared__ int sd[1024];
  int i = blockIdx.x*1024 + (int)threadIdx.x;
  int v = (i < NN) ? cnt[i] : 0;
  sd[threadIdx.x] = v;
  __syncthreads();
  #pragma unroll
  for (int ofs = 1; ofs < 1024; ofs <<= 1){
    int t = (threadIdx.x >= (unsigned)ofs) ? sd[threadIdx.x - ofs] : 0;
    __syncthreads();
    sd[threadIdx.x] += t;
    __syncthreads();
  }
  if (i < NN) incl[i] = sd[threadIdx.x];
  if (threadIdx.x == 1023) bsum[blockIdx.x] = sd[1023];
}
__global__ void k_scanB(const int* __restrict__ bsum, int* __restrict__ boff, int nb){
  if (threadIdx.x == 0){
    int acc = 0;
    for (int b = 0; b < nb; ++b){ boff[b] = acc; acc += bsum[b]; }
    boff[nb] = acc;
  }
}
__global__ void __launch_bounds__(1024) k_scanC(const int* __restrict__ cnt,
    const int* __restrict__ incl, const int* __restrict__ boff,
    int* __restrict__ rowstart, int* __restrict__ cursor, float* __restrict__ inv){
  int i = blockIdx.x*1024 + (int)threadIdx.x;
  if (i < NN){
    int c = cnt[i];
    int start = boff[blockIdx.x] + incl[i] - c;
    rowstart[i] = start;
    cursor[i]   = start;
    inv[i] = 1.f / fmaxf((float)c, 1.f);
  }
  if (blockIdx.x == 0 && threadIdx.x == 0) rowstart[NN] = boff[gridDim.x];
}

__global__ void k_fill(const int* __restrict__ ei0, const int* __restrict__ ei1,
                       int* __restrict__ cursor, int* __restrict__ perm,
                       int2* __restrict__ eidx2){
  int t = blockIdx.x*blockDim.x + threadIdx.x;
  if (t < EE){
    int n1 = ei1[t];
    int pos = atomicAdd(cursor + n1, 1);
    perm[pos] = t;
    int2 v; v.x = ei0[t]; v.y = n1;
    eidx2[pos] = v;
  }
}

// ---------------------------------------------------------------- encoder
template<int FIN, bool ISNODE>
__global__ void __launch_bounds__(256) k_encoder(
    const float* __restrict__ xin, const float* __restrict__ mv, const float* __restrict__ sv,
    const float* __restrict__ w0,  const float* __restrict__ b0,
    const bf16_t* __restrict__ W1p, const float* __restrict__ b1,
    const bf16_t* __restrict__ W2p, const float* __restrict__ b2,
    const float* __restrict__ gg,  const float* __restrict__ bb,
    float* __restrict__ outf, bf16_t* __restrict__ outb, bf16_t* __restrict__ outb2,
    const int* __restrict__ perm, int nblk)
{
  __shared__ bf16_t z0s[4][16][136];
  __shared__ bf16_t z1s[4][16][136];
  const int bid = blockIdx.x; const int c = bid / nblk; const int b = bid - c*nblk;
  if constexpr (ISNODE){
    xin  += (size_t)c*NN*FIN;
    outf += (size_t)c*NHD;
    outb += (size_t)c*NHD;
  }
  const int tid = threadIdx.x;
  const int w = tid >> 6, l = tid & 63, r = l & 15, grp = l >> 4;
  const int rowbase = b*64 + w*16;
  const int row = rowbase + r;
  const int src = perm ? perm[row] : row;

  float xn[FIN];
  #pragma unroll
  for (int f = 0; f < FIN; ++f) xn[f] = (xin[(size_t)src*FIN + f] - mv[f]) / sv[f];
  #pragma unroll
  for (int q = 0; q < 32; ++q){
    int cc = grp*32 + q;
    float a = b0[cc];
    #pragma unroll
    for (int f = 0; f < FIN; ++f) a += xn[f] * w0[f*HD + cc];
    z0s[w][r][cc] = (bf16_t)elu(a);
  }
  __syncthreads();

  bf16x8 a1[4];
  #pragma unroll
  for (int kt = 0; kt < 4; ++kt) a1[kt] = *(const bf16x8*)&z0s[w][r][kt*32 + grp*8];
  #pragma unroll
  for (int nt = 0; nt < 8; ++nt){
    int cc = nt*16 + r;
    float bv = b1[cc];
    f32x4 acc = {bv, bv, bv, bv};
    #pragma unroll
    for (int kt = 0; kt < 4; ++kt){
      bf16x8 bfr = *(const bf16x8*)(W1p + ((kt*4 + grp)*HD + cc)*8);
      acc = mfma16(a1[kt], bfr, acc);
    }
    #pragma unroll
    for (int i = 0; i < 4; ++i) z1s[w][grp*4 + i][cc] = (bf16_t)elu(acc[i]);
  }
  __syncthreads();

  bf16x8 a2[4];
  #pragma unroll
  for (int kt = 0; kt < 4; ++kt) a2[kt] = *(const bf16x8*)&z1s[w][r][kt*32 + grp*8];
  f32x4 et[8];
  #pragma unroll
  for (int nt = 0; nt < 8; ++nt){
    int cc = nt*16 + r;
    float bv = b2[cc];
    f32x4 acc = {bv, bv, bv, bv};
    #pragma unroll
    for (int kt = 0; kt < 4; ++kt){
      bf16x8 bfr = *(const bf16x8*)(W2p + ((kt*4 + grp)*HD + cc)*8);
      acc = mfma16(a2[kt], bfr, acc);
    }
    et[nt] = acc;
  }

  f32x4 s = {0,0,0,0}, sq = {0,0,0,0};
  #pragma unroll
  for (int nt = 0; nt < 8; ++nt)
    #pragma unroll
    for (int i = 0; i < 4; ++i){ float v = et[nt][i]; s[i] += v; sq[i] += v*v; }
  #pragma unroll
  for (int m = 1; m < 16; m <<= 1)
    #pragma unroll
    for (int i = 0; i < 4; ++i){ s[i] += __shfl_xor(s[i], m, 64); sq[i] += __shfl_xor(sq[i], m, 64); }
  f32x4 mean, rstd;
  #pragma unroll
  for (int i = 0; i < 4; ++i){
    float mu = s[i] * (1.f/HD);
    float va = sq[i] * (1.f/HD) - mu*mu;
    mean[i] = mu; rstd[i] = rsqrtf(va + 1e-5f);
  }
  #pragma unroll
  for (int nt = 0; nt < 8; ++nt){
    int cc = nt*16 + r;
    float gv = gg[cc], bv = bb[cc];
    #pragma unroll
    for (int i = 0; i < 4; ++i){
      float o = (et[nt][i] - mean[i]) * rstd[i] * gv + bv;
      size_t oidx = (size_t)(rowbase + grp*4 + i)*HD + cc;
      bf16_t ob = (bf16_t)o;
      outb[oidx] = ob;
      if (outb2) outb2[oidx] = ob;
      if constexpr (ISNODE) outf[oidx] = o;
    }
  }
}

// ---------------------------------------------------------------- h-partials
__global__ void __launch_bounds__(256) k_hpartial(
    const bf16_t* __restrict__ hbf,
    const bf16_t* __restrict__ Wap, const bf16_t* __restrict__ Wbp,
    bf16_t* __restrict__ p0, bf16_t* __restrict__ p1, int nblk)
{
  const int bid = blockIdx.x; const int c = bid / nblk; const int b = bid - c*nblk;
  hbf += (size_t)c*NHD; p0 += (size_t)c*NHD; p1 += (size_t)c*NHD;
  const int tid = threadIdx.x;
  const int w = tid >> 6, l = tid & 63, r = l & 15, grp = l >> 4;
  const int rowbase = b*64 + w*16;
  const int row = rowbase + r;

  bf16x8 afr[4];
  #pragma unroll
  for (int kt = 0; kt < 4; ++kt)
    afr[kt] = *(const bf16x8*)(hbf + (size_t)row*HD + kt*32 + grp*8);

  #pragma unroll
  for (int nt = 0; nt < 8; ++nt){
    int cc = nt*16 + r;
    f32x4 a0 = {0,0,0,0}, a1 = {0,0,0,0};
    #pragma unroll
    for (int kt = 0; kt < 4; ++kt){
      bf16x8 bfa = *(const bf16x8*)(Wap + ((kt*4 + grp)*HD + cc)*8);
      bf16x8 bfb = *(const bf16x8*)(Wbp + ((kt*4 + grp)*HD + cc)*8);
      a0 = mfma16(afr[kt], bfa, a0);
      a1 = mfma16(afr[kt], bfb, a1);
    }
    #pragma unroll
    for (int i = 0; i < 4; ++i){
      size_t oidx = (size_t)(rowbase + grp*4 + i)*HD + cc;
      p0[oidx] = (bf16_t)a0[i];
      p1[oidx] = (bf16_t)a1[i];
    }
  }
}

// ---------------------------------------------------------------- edge MLP step
// e_out = LN(e_in + MLP2(ELU(p0[ei0] + p1[ei1] + e_in@W0e + b0)))
// R12 inner structure + (a) bijective XCD-aware block swizzle (target-sorted
// edges => neighbor blocks share p1 rows; keep them on one XCD's L2) and
// (b) residual loads hoisted before MLP1 (drain under the MFMA phases).
__global__ void __launch_bounds__(256) k_edge_mlp(
    const bf16_t* __restrict__ p0g, const bf16_t* __restrict__ p1g,
    const bf16_t* e_in, bf16_t* e_out,
    const bf16_t* __restrict__ W0ep, const float* __restrict__ b0,
    const bf16_t* __restrict__ W1p, const float* __restrict__ b1,
    const float* __restrict__ gg,  const float* __restrict__ bb,
    const int2* __restrict__ eidx2, int nblk)
{
  __shared__ bf16_t z1s_all[4][16][136];
  // bijective XCD swizzle (m204 variant; grid not necessarily %8==0)
  const int G = gridDim.x;
  {
  }
  int bid0 = blockIdx.x;
  int qq = G >> 3, rr8 = G & 7;
  int xcd = bid0 & 7, idx8 = bid0 >> 3;
  int bid = (xcd < rr8 ? xcd*(qq+1) : rr8*(qq+1) + (xcd-rr8)*qq) + idx8;
  const int c = bid / nblk; const int b = bid - c*nblk;
  p0g += (size_t)c*NHD; p1g += (size_t)c*NHD;
  e_in += (size_t)c*EHD; e_out += (size_t)c*EHD;
  const int tid = threadIdx.x;
  const int w = tid >> 6, l = tid & 63, r = l & 15, grp = l >> 4;
  const int rowbase = b*64 + w*16;
  const int row = rowbase + r;
  bf16_t (*z1)[136] = z1s_all[w];

  // ---- stage partial sums: lane handles row sr = l>>2, cols [(l&3)*32, +32)
  {
    const int sr = l >> 2, cq = (l & 3)*32;
    const int2 nnS = eidx2[rowbase + sr];
    const bf16_t* P0 = p0g + (size_t)nnS.x*HD + cq;
    const bf16_t* P1 = p1g + (size_t)nnS.y*HD + cq;
    #pragma unroll
    for (int q = 0; q < 4; ++q){
      bf16x8 u = *(const bf16x8*)(P0 + q*8);
      bf16x8 v = *(const bf16x8*)(P1 + q*8);
      bf16x8 sm;
      #pragma unroll
      for (int i = 0; i < 8; ++i) sm[i] = (bf16_t)((float)u[i] + (float)v[i]);
      *(bf16x8*)&z1[sr][cq + q*8] = sm;
    }
  }

  bf16x8 afr[4];
  #pragma unroll
  for (int kt = 0; kt < 4; ++kt)
    afr[kt] = *(const bf16x8*)(e_in + (size_t)row*HD + kt*32 + grp*8);

  // hoisted residual loads (issue burst; drain under MLP1/MLP2 compute)
  float resv[8][4];
  #pragma unroll
  for (int nt = 0; nt < 8; ++nt)
    #pragma unroll
    for (int i = 0; i < 4; ++i)
      resv[nt][i] = (float)e_in[(size_t)(rowbase + grp*4 + i)*HD + nt*16 + r];

  __builtin_amdgcn_wave_barrier();

  // MLP1 (e-part only, K=128) + partial add + ELU, in-place in z1
  #pragma unroll
  for (int nt = 0; nt < 8; ++nt){
    int cc = nt*16 + r;
    float bv = b0[cc];
    f32x4 acc = {bv, bv, bv, bv};
    #pragma unroll
    for (int kt = 0; kt < 4; ++kt){
      bf16x8 bfr = *(const bf16x8*)(W0ep + ((kt*4 + grp)*HD + cc)*8);
      acc = mfma16(afr[kt], bfr, acc);
    }
    #pragma unroll
    for (int i = 0; i < 4; ++i){
      float pv = (float)z1[grp*4 + i][cc];
      z1[grp*4 + i][cc] = (bf16_t)elu(acc[i] + pv);
    }
  }
  __builtin_amdgcn_wave_barrier();

  bf16x8 a2[4];
  #pragma unroll
  for (int kt = 0; kt < 4; ++kt) a2[kt] = *(const bf16x8*)&z1[r][kt*32 + grp*8];
  f32x4 et[8];
  #pragma unroll
  for (int nt = 0; nt < 8; ++nt){
    int cc = nt*16 + r;
    float bv = b1[cc];
    f32x4 acc = {bv, bv, bv, bv};
    #pragma unroll
    for (int kt = 0; kt < 4; ++kt){
      bf16x8 bfr = *(const bf16x8*)(W1p + ((kt*4 + grp)*HD + cc)*8);
      acc = mfma16(a2[kt], bfr, acc);
    }
    et[nt] = acc;
  }

  // residual + LN (residual values already in registers)
  f32x4 s = {0,0,0,0}, sq = {0,0,0,0};
  #pragma unroll
  for (int nt = 0; nt < 8; ++nt){
    #pragma unroll
    for (int i = 0; i < 4; ++i){
      float v = et[nt][i] + resv[nt][i];
      et[nt][i] = v; s[i] += v; sq[i] += v*v;
    }
  }
  #pragma unroll
  for (int m = 1; m < 16; m <<= 1)
    #pragma unroll
    for (int i = 0; i < 4; ++i){ s[i] += __shfl_xor(s[i], m, 64); sq[i] += __shfl_xor(sq[i], m, 64); }
  f32x4 mean, rstd;
  #pragma unroll
  for (int i = 0; i < 4; ++i){
    float mu = s[i] * (1.f/HD);
    float va = sq[i] * (1.f/HD) - mu*mu;
    mean[i] = mu; rstd[i] = rsqrtf(va + 1e-5f);
  }
  #pragma unroll
  for (int nt = 0; nt < 8; ++nt){
    int cc = nt*16 + r;
    float gv = gg[cc], bv = bb[cc];
    #pragma unroll
    for (int i = 0; i < 4; ++i)
      e_out[(size_t)(rowbase + grp*4 + i)*HD + cc] =
          (bf16_t)((et[nt][i] - mean[i]) * rstd[i] * gv + bv);
  }
}

// ---------------------------------------------------------------- node MLP step
// h = LN(h + MLP2(ELU(MLP1(concat[h, agg])))) with segment-mean agg fused
template<bool DOPART>
__global__ void __launch_bounds__(256) k_node_mlp(
    bf16_t* hbf, const bf16_t* __restrict__ eg,
    const int* __restrict__ rowst, const float* __restrict__ inv,
    const bf16_t* __restrict__ W0p, const float* __restrict__ b0,
    const bf16_t* __restrict__ W1p, const float* __restrict__ b1,
    const float* __restrict__ gg,  const float* __restrict__ bb,
    float* hout,
    const bf16_t* __restrict__ Wap, const bf16_t* __restrict__ Wbp,
    bf16_t* __restrict__ p0, bf16_t* __restrict__ p1, int nblk)
{
  __shared__ bf16_t z1s[4][16][136];
  const int bid = blockIdx.x; const int c = bid / nblk; const int b = bid - c*nblk;
  hbf += (size_t)c*NHD; eg += (size_t)c*EHD; hout += (size_t)c*NHD;
  if constexpr (DOPART){ p0 += (size_t)c*NHD; p1 += (size_t)c*NHD; }
  const int tid = threadIdx.x;
  const int w = tid >> 6, l = tid & 63, r = l & 15, grp = l >> 4;
  const int rowbase = b*64 + w*16;
  const int row = rowbase + r;

  // ---- fused segment-mean (replaces k_agg) -> afr[4..7]
  bf16x8 afr[8];
  {
    int es = rowst[row], ef = rowst[row+1];
    float a0[8] = {0,0,0,0,0,0,0,0}, a1[8] = {0,0,0,0,0,0,0,0};
    float a2[8] = {0,0,0,0,0,0,0,0}, a3[8] = {0,0,0,0,0,0,0,0};
    for (int ed = es; ed < ef; ++ed){
      const bf16_t* ep = eg + (size_t)ed*HD + grp*8;
      bf16x8 v0 = *(const bf16x8*)(ep);
      bf16x8 v1 = *(const bf16x8*)(ep + 32);
      bf16x8 v2 = *(const bf16x8*)(ep + 64);
      bf16x8 v3 = *(const bf16x8*)(ep + 96);
      #pragma unroll
      for (int i = 0; i < 8; ++i){
        a0[i] += (float)v0[i]; a1[i] += (float)v1[i];
        a2[i] += (float)v2[i]; a3[i] += (float)v3[i];
      }
    }
    float sc = inv[row];
    #pragma unroll
    for (int i = 0; i < 8; ++i){
      afr[4][i] = (bf16_t)(a0[i]*sc);
      afr[5][i] = (bf16_t)(a1[i]*sc);
      afr[6][i] = (bf16_t)(a2[i]*sc);
      afr[7][i] = (bf16_t)(a3[i]*sc);
    }
  }
  #pragma unroll
  for (int kt = 0; kt < 4; ++kt)
    afr[kt] = *(const bf16x8*)(hbf + (size_t)row*HD + kt*32 + grp*8);

  #pragma unroll
  for (int nt = 0; nt < 8; ++nt){
    int cc = nt*16 + r;
    float bv = b0[cc];
    f32x4 acc = {bv, bv, bv, bv};
    #pragma unroll
    for (int kt = 0; kt < 8; ++kt){
      bf16x8 bfr = *(const bf16x8*)(W0p + ((kt*4 + grp)*HD + cc)*8);
      acc = mfma16(afr[kt], bfr, acc);
    }
    #pragma unroll
    for (int i = 0; i < 4; ++i) z1s[w][grp*4 + i][cc] = (bf16_t)elu(acc[i]);
  }
  __syncthreads();

  bf16x8 a2f[4];
  #pragma unroll
  for (int kt = 0; kt < 4; ++kt) a2f[kt] = *(const bf16x8*)&z1s[w][r][kt*32 + grp*8];
  f32x4 et[8];
  #pragma unroll
  for (int nt = 0; nt < 8; ++nt){
    int cc = nt*16 + r;
    float bv = b1[cc];
    f32x4 acc = {bv, bv, bv, bv};
    #pragma unroll
    for (int kt = 0; kt < 4; ++kt){
      bf16x8 bfr = *(const bf16x8*)(W1p + ((kt*4 + grp)*HD + cc)*8);
      acc = mfma16(a2f[kt], bfr, acc);
    }
    et[nt] = acc;
  }

  f32x4 s = {0,0,0,0}, sq = {0,0,0,0};
  #pragma unroll
  for (int nt = 0; nt < 8; ++nt){
    int cc = nt*16 + r;
    #pragma unroll
    for (int i = 0; i < 4; ++i){
      float v = et[nt][i] + hout[(size_t)(rowbase + grp*4 + i)*HD + cc];
      et[nt][i] = v; s[i] += v; sq[i] += v*v;
    }
  }
  #pragma unroll
  for (int m = 1; m < 16; m <<= 1)
    #pragma unroll
    for (int i = 0; i < 4; ++i){ s[i] += __shfl_xor(s[i], m, 64); sq[i] += __shfl_xor(sq[i], m, 64); }
  f32x4 mean, rstd;
  #pragma unroll
  for (int i = 0; i < 4; ++i){
    float mu = s[i] * (1.f/HD);
    float va = sq[i] * (1.f/HD) - mu*mu;
    mean[i] = mu; rstd[i] = rsqrtf(va + 1e-5f);
  }
  #pragma unroll
  for (int nt = 0; nt < 8; ++nt){
    int cc = nt*16 + r;
    float gv = gg[cc], bv = bb[cc];
    #pragma unroll
    for (int i = 0; i < 4; ++i){
      float o = (et[nt][i] - mean[i]) * rstd[i] * gv + bv;
      size_t oidx = (size_t)(rowbase + grp*4 + i)*HD + cc;
      bf16_t ob = (bf16_t)o;
      hout[oidx] = o;
      hbf[oidx]  = ob;
      if constexpr (DOPART) z1s[w][grp*4 + i][cc] = ob;
    }
  }

  if constexpr (DOPART){
    __builtin_amdgcn_wave_barrier();
    bf16x8 ah[4];
    #pragma unroll
    for (int kt = 0; kt < 4; ++kt) ah[kt] = *(const bf16x8*)&z1s[w][r][kt*32 + grp*8];
    #pragma unroll
    for (int nt = 0; nt < 8; ++nt){
      int cc = nt*16 + r;
      f32x4 a0 = {0,0,0,0}, a1 = {0,0,0,0};
      #pragma unroll
      for (int kt = 0; kt < 4; ++kt){
        bf16x8 bfa = *(const bf16x8*)(Wap + ((kt*4 + grp)*HD + cc)*8);
        bf16x8 bfb = *(const bf16x8*)(Wbp + ((kt*4 + grp)*HD + cc)*8);
        a0 = mfma16(ah[kt], bfa, a0);
        a1 = mfma16(ah[kt], bfb, a1);
      }
      #pragma unroll
      for (int i = 0; i < 4; ++i){
        size_t oidx = (size_t)(rowbase + grp*4 + i)*HD + cc;
        p0[oidx] = (bf16_t)a0[i];
        p1[oidx] = (bf16_t)a1[i];
      }
    }
  }
}

// ---------------------------------------------------------------- host
extern "C" void kernel_launch(void* const* d_in, const int* in_sizes, int n_in,
                              void* d_out, int out_size, void* d_ws, size_t ws_size,
                              hipStream_t stream)
{
  (void)in_sizes; (void)n_in; (void)out_size;
  const float* x         = (const float*)d_in[0];
  const float* edge_attr = (const float*)d_in[1];
  const float* mvx = (const float*)d_in[2];
  const float* svx = (const float*)d_in[3];
  const float* mve = (const float*)d_in[4];
  const float* sve = (const float*)d_in[5];
  const float* nenc_w0 = (const float*)d_in[6];
  const float* nenc_b0 = (const float*)d_in[7];
  const float* nenc_w1 = (const float*)d_in[8];
  const float* nenc_b1 = (const float*)d_in[9];
  const float* nenc_w2 = (const float*)d_in[10];
  const float* nenc_b2 = (const float*)d_in[11];
  const float* nenc_g  = (const float*)d_in[12];
  const float* nenc_be = (const float*)d_in[13];
  const float* eenc_w0 = (const float*)d_in[14];
  const float* eenc_b0 = (const float*)d_in[15];
  const float* eenc_w1 = (const float*)d_in[16];
  const float* eenc_b1 = (const float*)d_in[17];
  const float* eenc_w2 = (const float*)d_in[18];
  const float* eenc_b2 = (const float*)d_in[19];
  const float* eenc_g  = (const float*)d_in[20];
  const float* eenc_be = (const float*)d_in[21];
  const float* emp_w0 = (const float*)d_in[22];
  const float* emp_b0 = (const float*)d_in[23];
  const float* emp_w1 = (const float*)d_in[24];
  const float* emp_b1 = (const float*)d_in[25];
  const float* emp_g  = (const float*)d_in[26];
  const float* emp_be = (const float*)d_in[27];
  const float* nmp_w0 = (const float*)d_in[28];
  const float* nmp_b0 = (const float*)d_in[29];
  const float* nmp_w1 = (const float*)d_in[30];
  const float* nmp_b1 = (const float*)d_in[31];
  const float* nmp_g  = (const float*)d_in[32];
  const float* nmp_be = (const float*)d_in[33];
  const int* eidx = (const int*)d_in[34];
  const int* ei0 = eidx;
  const int* ei1 = eidx + EE;
  float* out = (float*)d_out;

  PackArgs pa;
  const float* srcs[30] = {
    eenc_w0, eenc_w1, eenc_w2, nenc_w0, nenc_w1, nenc_w2,
    emp_w0,           emp_w0 + 49152,           emp_w0 + 2*49152,           emp_w0 + 3*49152,
    emp_w0 + 16384,   emp_w0 + 49152 + 16384,   emp_w0 + 2*49152 + 16384,   emp_w0 + 3*49152 + 16384,
    emp_w0 + 32768,   emp_w0 + 49152 + 32768,   emp_w0 + 2*49152 + 32768,   emp_w0 + 3*49152 + 32768,
    emp_w1, emp_w1 + 16384, emp_w1 + 2*16384, emp_w1 + 3*16384,
    nmp_w0, nmp_w0 + 32768, nmp_w0 + 2*32768, nmp_w0 + 3*32768,
    nmp_w1, nmp_w1 + 16384, nmp_w1 + 2*16384, nmp_w1 + 3*16384 };
  const int KsA[30] = {FEE,128,128,FNN,128,128,
                       128,128,128,128, 128,128,128,128, 128,128,128,128,
                       128,128,128,128, 256,256,256,256, 128,128,128,128};
  int offs[30]; int tot = 0;
  for (int i = 0; i < 30; ++i){
    pa.j[i].src = srcs[i]; pa.j[i].K = KsA[i];
    offs[i] = tot; tot += ((KsA[i] + 31) & ~31) * HD;
  }

  const int NBn = NN/64;
  const int NBe = EE/64;
  const int NB  = (NN + 1023)/1024;

  size_t need_merged = 2*EHD*2 + 8*NHD*2 + (size_t)NN*4 + (size_t)(NN+1)*4 + 64
                     + (size_t)EE*4 + (size_t)EE*8 + (size_t)tot*2 + 1024;

  char* ws = (char*)d_ws;

  if (ws_size >= need_merged){
    // ================= MERGED PATH: both chunks per dispatch =================
    size_t off = 0;
    bf16_t* e_cur = (bf16_t*)(ws + off); off += 2*EHD*2;
    bf16_t* hbf   = (bf16_t*)(ws + off); off += 2*NHD*2;
    bf16_t* agg   = (bf16_t*)(ws + off); size_t agg_off = off; off += 2*NHD*2; (void)agg;
    bf16_t* p0    = (bf16_t*)(ws + off); off += 2*NHD*2;
    bf16_t* p1    = (bf16_t*)(ws + off); off += 2*NHD*2;
    float*  inv   = (float*)(ws + off);  off += (size_t)NN*4;
    int*    rowst = (int*)(ws + off);    off += (size_t)(NN+1)*4 + 12;
    int*    perm  = (int*)(ws + off);    off += (size_t)EE*4;
    int2*   eidx2 = (int2*)(ws + off);   off += (size_t)EE*8;
    bf16_t* wpk   = (bf16_t*)(ws + off);
    int*    cnt_i = (int*)(ws + agg_off);
    int*    curs  = (int*)(ws + agg_off + (size_t)NN*4);
    int*    incl  = (int*)(ws + agg_off + (size_t)2*NN*4);
    int*    bsum  = (int*)(ws + agg_off + (size_t)3*NN*4);
    int*    boff  = (int*)(ws + agg_off + (size_t)3*NN*4 + 256);

    hipMemsetAsync(cnt_i, 0, NN*sizeof(int), stream);
    k_cnt<<<(EE + 255)/256, 256, 0, stream>>>(ei1, cnt_i);
    k_scanA<<<NB, 1024, 0, stream>>>(cnt_i, incl, bsum);
    k_scanB<<<1, 64, 0, stream>>>(bsum, boff, NB);
    k_scanC<<<NB, 1024, 0, stream>>>(cnt_i, incl, boff, rowst, curs, inv);
    k_fill<<<(EE + 255)/256, 256, 0, stream>>>(ei0, ei1, curs, perm, eidx2);
    k_pack<<<(tot + 255)/256, 256, 0, stream>>>(pa, wpk);

    k_encoder<FEE,false><<<NBe, 256, 0, stream>>>(edge_attr, mve, sve,
        eenc_w0, eenc_b0, wpk + offs[1], eenc_b1, wpk + offs[2], eenc_b2,
        eenc_g, eenc_be, nullptr, e_cur, e_cur + EHD, perm, NBe);
    k_encoder<FNN,true><<<2*NBn, 256, 0, stream>>>(x, mvx, svx,
        nenc_w0, nenc_b0, wpk + offs[4], nenc_b1, wpk + offs[5], nenc_b2,
        nenc_g, nenc_be, out, hbf, nullptr, nullptr, NBn);
    k_hpartial<<<2*NBn, 256, 0, stream>>>(hbf, wpk + offs[6], wpk + offs[10], p0, p1, NBn);

    for (int s = 0; s < SS; ++s){
      k_edge_mlp<<<2*NBe, 256, 0, stream>>>(p0, p1, e_cur, e_cur,
          wpk + offs[14+s], emp_b0 + s*HD, wpk + offs[18+s], emp_b1 + s*HD,
          emp_g + s*HD, emp_be + s*HD, eidx2, NBe);
      if (s < SS-1){
        k_node_mlp<true><<<2*NBn, 256, 0, stream>>>(hbf, e_cur, rowst, inv,
            wpk + offs[22+s], nmp_b0 + s*HD, wpk + offs[26+s], nmp_b1 + s*HD,
            nmp_g + s*HD, nmp_be + s*HD, out,
            wpk + offs[6+(s+1)], wpk + offs[10+(s+1)], p0, p1, NBn);
      } else {
        k_node_mlp<false><<<2*NBn, 256, 0, stream>>>(hbf, e_cur, rowst, inv,
            wpk + offs[22+s], nmp_b0 + s*HD, wpk + offs[26+s], nmp_b1 + s*HD,
            nmp_g + s*HD, nmp_be + s*HD, out,
            nullptr, nullptr, nullptr, nullptr, NBn);
      }
    }
  } else {
    // ================= FALLBACK (sequential chunks) =================
    size_t off = 0;
    bf16_t* e_cur = (bf16_t*)(ws + off); off += EHD*2;
    bf16_t* e0    = (bf16_t*)(ws + off); off += EHD*2;
    bf16_t* hbf   = (bf16_t*)(ws + off); off += NHD*2;
    bf16_t* agg   = (bf16_t*)(ws + off); size_t agg_off = off; off += NHD*2; (void)agg;
    bf16_t* p0    = (bf16_t*)(ws + off); off += NHD*2;
    bf16_t* p1    = (bf16_t*)(ws + off); off += NHD*2;
    float*  inv   = (float*)(ws + off);  off += (size_t)NN*4;
    int*    rowst = (int*)(ws + off);    off += (size_t)(NN+1)*4 + 12;
    int*    perm  = (int*)(ws + off);    off += (size_t)EE*4;
    int2*   eidx2 = (int2*)(ws + off);   off += (size_t)EE*8;
    bf16_t* wpk   = (bf16_t*)(ws + off);
    int*    cnt_i = (int*)(ws + agg_off);
    int*    curs  = (int*)(ws + agg_off + (size_t)NN*4);
    int*    incl  = (int*)(ws + agg_off + (size_t)2*NN*4);
    int*    bsum  = (int*)(ws + agg_off + (size_t)3*NN*4);
    int*    boff  = (int*)(ws + agg_off + (size_t)3*NN*4 + 256);

    hipMemsetAsync(cnt_i, 0, NN*sizeof(int), stream);
    k_cnt<<<(EE + 255)/256, 256, 0, stream>>>(ei1, cnt_i);
    k_scanA<<<NB, 1024, 0, stream>>>(cnt_i, incl, bsum);
    k_scanB<<<1, 64, 0, stream>>>(bsum, boff, NB);
    k_scanC<<<NB, 1024, 0, stream>>>(cnt_i, incl, boff, rowst, curs, inv);
    k_fill<<<(EE + 255)/256, 256, 0, stream>>>(ei0, ei1, curs, perm, eidx2);
    k_pack<<<(tot + 255)/256, 256, 0, stream>>>(pa, wpk);

    k_encoder<FEE,false><<<NBe, 256, 0, stream>>>(edge_attr, mve, sve,
        eenc_w0, eenc_b0, wpk + offs[1], eenc_b1, wpk + offs[2], eenc_b2,
        eenc_g, eenc_be, nullptr, e0, nullptr, perm, NBe);

    for (int c = 0; c < 2; ++c){
      float* hout = out + (size_t)c*NHD;
      k_encoder<FNN,true><<<NBn, 256, 0, stream>>>(x + (size_t)c*NN*FNN, mvx, svx,
          nenc_w0, nenc_b0, wpk + offs[4], nenc_b1, wpk + offs[5], nenc_b2,
          nenc_g, nenc_be, hout, hbf, nullptr, nullptr, NBn);
      k_hpartial<<<NBn, 256, 0, stream>>>(hbf, wpk + offs[6], wpk + offs[10], p0, p1, NBn);
      for (int s = 0; s < SS; ++s){
        const bf16_t* e_in = (s == 0) ? e0 : e_cur;
        k_edge_mlp<<<NBe, 256, 0, stream>>>(p0, p1, e_in, e_cur,
            wpk + offs[14+s], emp_b0 + s*HD, wpk + offs[18+s], emp_b1 + s*HD,
            emp_g + s*HD, emp_be + s*HD, eidx2, NBe);
        if (s < SS-1){
          k_node_mlp<true><<<NBn, 256, 0, stream>>>(hbf, e_cur, rowst, inv,
              wpk + offs[22+s], nmp_b0 + s*HD, wpk + offs[26+s], nmp_b1 + s*HD,
              nmp_g + s*HD, nmp_be + s*HD, hout,
              wpk + offs[6+(s+1)], wpk + offs[10+(s+1)], p0, p1, NBn);
        } else {
          k_node_mlp<false><<<NBn, 256, 0, stream>>>(hbf, e_cur, rowst, inv,
              wpk + offs[22+s], nmp_b0 + s*HD, wpk + offs[26+s], nmp_b1 + s*HD,
              nmp_g + s*HD, nmp_be + s*HD, hout,
              nullptr, nullptr, nullptr, nullptr, NBn);
        }
      }
    }
  }
}

// Round 16
// 951.630 us; speedup vs baseline: 1.2273x; 1.2273x over previous
//
#include <hip/hip_runtime.h>
#include <math.h>

constexpr int HD  = 128;     // hidden
constexpr int FNN = 6;       // node in-features
constexpr int FEE = 3;       // edge in-features
constexpr int NN  = 40000;   // nodes per chunk
constexpr int EE  = 240000;  // edges
constexpr int SS  = 4;       // mp steps
constexpr size_t NHD = (size_t)NN*HD;
constexpr size_t EHD = (size_t)EE*HD;

typedef __bf16 bf16_t;
typedef bf16_t bf16x8 __attribute__((ext_vector_type(8)));
typedef float  f32x4  __attribute__((ext_vector_type(4)));

__device__ __forceinline__ f32x4 mfma16(bf16x8 a, bf16x8 b, f32x4 c){
  return __builtin_amdgcn_mfma_f32_16x16x32_bf16(a, b, c, 0, 0, 0);
}
__device__ __forceinline__ float elu(float v){ return v > 0.f ? v : __expf(v) - 1.f; }

// ---------------------------------------------------------------- weight pack
struct PackJob { const float* src; int K; };
struct PackArgs { PackJob j[30]; };

__global__ void __launch_bounds__(256) k_pack(PackArgs pa, bf16_t* __restrict__ dst){
  int gid = blockIdx.x*256 + threadIdx.x;
  int base = 0;
  #pragma unroll 1
  for (int i = 0; i < 30; ++i){
    int Kp = (pa.j[i].K + 31) & ~31;
    int sz = Kp * HD;
    if (gid < base + sz){
      int idx = gid - base;
      int jj = idx & 7, c = (idx >> 3) & 127, G = idx >> 10;
      int k = G*8 + jj;
      float v = (k < pa.j[i].K) ? pa.j[i].src[(size_t)k*HD + c] : 0.f;
      dst[base + idx] = (bf16_t)v;
      return;
    }
    base += sz;
  }
}

// ---------------------------------------------------------------- CSR build
__global__ void k_cnt(const int* __restrict__ ei1, int* __restrict__ cnt){
  int t = blockIdx.x*blockDim.x + threadIdx.x;
  if (t < EE) atomicAdd(cnt + ei1[t], 1);
}

__global__ void __launch_bounds__(1024) k_scanA(const int* __restrict__ cnt,
    int* __restrict__ incl, int* __restrict__ bsum){
  __shared__ int sd[1024];
  int i = blockIdx.x*1024 + (int)threadIdx.x;
  int v = (i < NN) ? cnt[i] : 0;
  sd[threadIdx.x] = v;
  __syncthreads();
  #pragma unroll
  for (int ofs = 1; ofs < 1024; ofs <<= 1){
    int t = (threadIdx.x >= (unsigned)ofs) ? sd[threadIdx.x - ofs] : 0;
    __syncthreads();
    sd[threadIdx.x] += t;
    __syncthreads();
  }
  if (i < NN) incl[i] = sd[threadIdx.x];
  if (threadIdx.x == 1023) bsum[blockIdx.x] = sd[1023];
}
__global__ void k_scanB(const int* __restrict__ bsum, int* __restrict__ boff, int nb){
  if (threadIdx.x == 0){
    int acc = 0;
    for (int b = 0; b < nb; ++b){ boff[b] = acc; acc += bsum[b]; }
    boff[nb] = acc;
  }
}
__global__ void __launch_bounds__(1024) k_scanC(const int* __restrict__ cnt,
    const int* __restrict__ incl, const int* __restrict__ boff,
    int* __restrict__ rowstart, int* __restrict__ cursor, float* __restrict__ inv){
  int i = blockIdx.x*1024 + (int)threadIdx.x;
  if (i < NN){
    int c = cnt[i];
    int start = boff[blockIdx.x] + incl[i] - c;
    rowstart[i] = start;
    cursor[i]   = start;
    inv[i] = 1.f / fmaxf((float)c, 1.f);
  }
  if (blockIdx.x == 0 && threadIdx.x == 0) rowstart[NN] = boff[gridDim.x];
}

__global__ void k_fill(const int* __restrict__ ei0, const int* __restrict__ ei1,
                       int* __restrict__ cursor, int* __restrict__ perm,
                       int2* __restrict__ eidx2){
  int t = blockIdx.x*blockDim.x + threadIdx.x;
  if (t < EE){
    int n1 = ei1[t];
    int pos = atomicAdd(cursor + n1, 1);
    perm[pos] = t;
    int2 v; v.x = ei0[t]; v.y = n1;
    eidx2[pos] = v;
  }
}

// ---------------------------------------------------------------- encoder
// 3-layer MLP + LN.  If DOPART (node encoder): also emits p0/p1 = h0 @ W0a/W0b
// for step 0, reusing the free wave-private z1s (same pattern as k_node_mlp).
template<int FIN, bool ISNODE, bool DOPART>
__global__ void __launch_bounds__(256) k_encoder(
    const float* __restrict__ xin, const float* __restrict__ mv, const float* __restrict__ sv,
    const float* __restrict__ w0,  const float* __restrict__ b0,
    const bf16_t* __restrict__ W1p, const float* __restrict__ b1,
    const bf16_t* __restrict__ W2p, const float* __restrict__ b2,
    const float* __restrict__ gg,  const float* __restrict__ bb,
    float* __restrict__ outf, bf16_t* __restrict__ outb, bf16_t* __restrict__ outb2,
    const int* __restrict__ perm, int nblk,
    const bf16_t* __restrict__ Wap, const bf16_t* __restrict__ Wbp,
    bf16_t* __restrict__ p0, bf16_t* __restrict__ p1)
{
  __shared__ bf16_t z0s[4][16][136];
  __shared__ bf16_t z1s[4][16][136];
  const int bid = blockIdx.x; const int c = bid / nblk; const int b = bid - c*nblk;
  if constexpr (ISNODE){
    xin  += (size_t)c*NN*FIN;
    outf += (size_t)c*NHD;
    outb += (size_t)c*NHD;
  }
  if constexpr (DOPART){ p0 += (size_t)c*NHD; p1 += (size_t)c*NHD; }
  const int tid = threadIdx.x;
  const int w = tid >> 6, l = tid & 63, r = l & 15, grp = l >> 4;
  const int rowbase = b*64 + w*16;
  const int row = rowbase + r;
  const int src = perm ? perm[row] : row;

  float xn[FIN];
  #pragma unroll
  for (int f = 0; f < FIN; ++f) xn[f] = (xin[(size_t)src*FIN + f] - mv[f]) / sv[f];
  #pragma unroll
  for (int q = 0; q < 32; ++q){
    int cc = grp*32 + q;
    float a = b0[cc];
    #pragma unroll
    for (int f = 0; f < FIN; ++f) a += xn[f] * w0[f*HD + cc];
    z0s[w][r][cc] = (bf16_t)elu(a);
  }
  __syncthreads();

  bf16x8 a1[4];
  #pragma unroll
  for (int kt = 0; kt < 4; ++kt) a1[kt] = *(const bf16x8*)&z0s[w][r][kt*32 + grp*8];
  #pragma unroll
  for (int nt = 0; nt < 8; ++nt){
    int cc = nt*16 + r;
    float bv = b1[cc];
    f32x4 acc = {bv, bv, bv, bv};
    #pragma unroll
    for (int kt = 0; kt < 4; ++kt){
      bf16x8 bfr = *(const bf16x8*)(W1p + ((kt*4 + grp)*HD + cc)*8);
      acc = mfma16(a1[kt], bfr, acc);
    }
    #pragma unroll
    for (int i = 0; i < 4; ++i) z1s[w][grp*4 + i][cc] = (bf16_t)elu(acc[i]);
  }
  __syncthreads();

  bf16x8 a2[4];
  #pragma unroll
  for (int kt = 0; kt < 4; ++kt) a2[kt] = *(const bf16x8*)&z1s[w][r][kt*32 + grp*8];
  f32x4 et[8];
  #pragma unroll
  for (int nt = 0; nt < 8; ++nt){
    int cc = nt*16 + r;
    float bv = b2[cc];
    f32x4 acc = {bv, bv, bv, bv};
    #pragma unroll
    for (int kt = 0; kt < 4; ++kt){
      bf16x8 bfr = *(const bf16x8*)(W2p + ((kt*4 + grp)*HD + cc)*8);
      acc = mfma16(a2[kt], bfr, acc);
    }
    et[nt] = acc;
  }

  f32x4 s = {0,0,0,0}, sq = {0,0,0,0};
  #pragma unroll
  for (int nt = 0; nt < 8; ++nt)
    #pragma unroll
    for (int i = 0; i < 4; ++i){ float v = et[nt][i]; s[i] += v; sq[i] += v*v; }
  #pragma unroll
  for (int m = 1; m < 16; m <<= 1)
    #pragma unroll
    for (int i = 0; i < 4; ++i){ s[i] += __shfl_xor(s[i], m, 64); sq[i] += __shfl_xor(sq[i], m, 64); }
  f32x4 mean, rstd;
  #pragma unroll
  for (int i = 0; i < 4; ++i){
    float mu = s[i] * (1.f/HD);
    float va = sq[i] * (1.f/HD) - mu*mu;
    mean[i] = mu; rstd[i] = rsqrtf(va + 1e-5f);
  }
  #pragma unroll
  for (int nt = 0; nt < 8; ++nt){
    int cc = nt*16 + r;
    float gv = gg[cc], bv = bb[cc];
    #pragma unroll
    for (int i = 0; i < 4; ++i){
      float o = (et[nt][i] - mean[i]) * rstd[i] * gv + bv;
      size_t oidx = (size_t)(rowbase + grp*4 + i)*HD + cc;
      bf16_t ob = (bf16_t)o;
      outb[oidx] = ob;
      if (outb2) outb2[oidx] = ob;
      if constexpr (ISNODE) outf[oidx] = o;
      if constexpr (DOPART) z1s[w][grp*4 + i][cc] = ob;  // stage h0 (wave-private)
    }
  }

  if constexpr (DOPART){
    __builtin_amdgcn_wave_barrier();
    bf16x8 ah[4];
    #pragma unroll
    for (int kt = 0; kt < 4; ++kt) ah[kt] = *(const bf16x8*)&z1s[w][r][kt*32 + grp*8];
    #pragma unroll
    for (int nt = 0; nt < 8; ++nt){
      int cc = nt*16 + r;
      f32x4 a0 = {0,0,0,0}, a1p = {0,0,0,0};
      #pragma unroll
      for (int kt = 0; kt < 4; ++kt){
        bf16x8 bfa = *(const bf16x8*)(Wap + ((kt*4 + grp)*HD + cc)*8);
        bf16x8 bfb = *(const bf16x8*)(Wbp + ((kt*4 + grp)*HD + cc)*8);
        a0  = mfma16(ah[kt], bfa, a0);
        a1p = mfma16(ah[kt], bfb, a1p);
      }
      #pragma unroll
      for (int i = 0; i < 4; ++i){
        size_t oidx = (size_t)(rowbase + grp*4 + i)*HD + cc;
        p0[oidx] = (bf16_t)a0[i];
        p1[oidx] = (bf16_t)a1p[i];
      }
    }
  }
}

// ---------------------------------------------------------------- edge MLP step
// e_out = LN(e_in + MLP2(ELU(p0[ei0] + p1[ei1] + e_in@W0e + b0)))   [R12-exact]
__global__ void __launch_bounds__(256) k_edge_mlp(
    const bf16_t* __restrict__ p0g, const bf16_t* __restrict__ p1g,
    const bf16_t* e_in, bf16_t* e_out,
    const bf16_t* __restrict__ W0ep, const float* __restrict__ b0,
    const bf16_t* __restrict__ W1p, const float* __restrict__ b1,
    const float* __restrict__ gg,  const float* __restrict__ bb,
    const int2* __restrict__ eidx2, int nblk)
{
  __shared__ bf16_t z1s_all[4][16][136];
  const int bid = blockIdx.x; const int c = bid / nblk; const int b = bid - c*nblk;
  p0g += (size_t)c*NHD; p1g += (size_t)c*NHD;
  e_in += (size_t)c*EHD; e_out += (size_t)c*EHD;
  const int tid = threadIdx.x;
  const int w = tid >> 6, l = tid & 63, r = l & 15, grp = l >> 4;
  const int rowbase = b*64 + w*16;
  const int row = rowbase + r;
  bf16_t (*z1)[136] = z1s_all[w];

  // ---- stage partial sums: lane handles row sr = l>>2, cols [(l&3)*32, +32)
  {
    const int sr = l >> 2, cq = (l & 3)*32;
    const int2 nnS = eidx2[rowbase + sr];
    const bf16_t* P0 = p0g + (size_t)nnS.x*HD + cq;
    const bf16_t* P1 = p1g + (size_t)nnS.y*HD + cq;
    #pragma unroll
    for (int q = 0; q < 4; ++q){
      bf16x8 u = *(const bf16x8*)(P0 + q*8);
      bf16x8 v = *(const bf16x8*)(P1 + q*8);
      bf16x8 sm;
      #pragma unroll
      for (int i = 0; i < 8; ++i) sm[i] = (bf16_t)((float)u[i] + (float)v[i]);
      *(bf16x8*)&z1[sr][cq + q*8] = sm;
    }
  }

  bf16x8 afr[4];
  #pragma unroll
  for (int kt = 0; kt < 4; ++kt)
    afr[kt] = *(const bf16x8*)(e_in + (size_t)row*HD + kt*32 + grp*8);
  __builtin_amdgcn_wave_barrier();

  // MLP1 (e-part only, K=128) + partial add + ELU, in-place in z1
  #pragma unroll
  for (int nt = 0; nt < 8; ++nt){
    int cc = nt*16 + r;
    float bv = b0[cc];
    f32x4 acc = {bv, bv, bv, bv};
    #pragma unroll
    for (int kt = 0; kt < 4; ++kt){
      bf16x8 bfr = *(const bf16x8*)(W0ep + ((kt*4 + grp)*HD + cc)*8);
      acc = mfma16(afr[kt], bfr, acc);
    }
    #pragma unroll
    for (int i = 0; i < 4; ++i){
      float pv = (float)z1[grp*4 + i][cc];
      z1[grp*4 + i][cc] = (bf16_t)elu(acc[i] + pv);
    }
  }
  __builtin_amdgcn_wave_barrier();

  bf16x8 a2[4];
  #pragma unroll
  for (int kt = 0; kt < 4; ++kt) a2[kt] = *(const bf16x8*)&z1[r][kt*32 + grp*8];
  f32x4 et[8];
  #pragma unroll
  for (int nt = 0; nt < 8; ++nt){
    int cc = nt*16 + r;
    float bv = b1[cc];
    f32x4 acc = {bv, bv, bv, bv};
    #pragma unroll
    for (int kt = 0; kt < 4; ++kt){
      bf16x8 bfr = *(const bf16x8*)(W1p + ((kt*4 + grp)*HD + cc)*8);
      acc = mfma16(a2[kt], bfr, acc);
    }
    et[nt] = acc;
  }

  // residual + LN
  f32x4 s = {0,0,0,0}, sq = {0,0,0,0};
  #pragma unroll
  for (int nt = 0; nt < 8; ++nt){
    int cc = nt*16 + r;
    #pragma unroll
    for (int i = 0; i < 4; ++i){
      float v = et[nt][i] + (float)e_in[(size_t)(rowbase + grp*4 + i)*HD + cc];
      et[nt][i] = v; s[i] += v; sq[i] += v*v;
    }
  }
  #pragma unroll
  for (int m = 1; m < 16; m <<= 1)
    #pragma unroll
    for (int i = 0; i < 4; ++i){ s[i] += __shfl_xor(s[i], m, 64); sq[i] += __shfl_xor(sq[i], m, 64); }
  f32x4 mean, rstd;
  #pragma unroll
  for (int i = 0; i < 4; ++i){
    float mu = s[i] * (1.f/HD);
    float va = sq[i] * (1.f/HD) - mu*mu;
    mean[i] = mu; rstd[i] = rsqrtf(va + 1e-5f);
  }
  #pragma unroll
  for (int nt = 0; nt < 8; ++nt){
    int cc = nt*16 + r;
    float gv = gg[cc], bv = bb[cc];
    #pragma unroll
    for (int i = 0; i < 4; ++i)
      e_out[(size_t)(rowbase + grp*4 + i)*HD + cc] =
          (bf16_t)((et[nt][i] - mean[i]) * rstd[i] * gv + bv);
  }
}

// ---------------------------------------------------------------- node MLP step
// h = LN(h + MLP2(ELU(MLP1(concat[h, agg])))) with segment-mean agg fused
template<bool DOPART>
__global__ void __launch_bounds__(256) k_node_mlp(
    bf16_t* hbf, const bf16_t* __restrict__ eg,
    const int* __restrict__ rowst, const float* __restrict__ inv,
    const bf16_t* __restrict__ W0p, const float* __restrict__ b0,
    const bf16_t* __restrict__ W1p, const float* __restrict__ b1,
    const float* __restrict__ gg,  const float* __restrict__ bb,
    float* hout,
    const bf16_t* __restrict__ Wap, const bf16_t* __restrict__ Wbp,
    bf16_t* __restrict__ p0, bf16_t* __restrict__ p1, int nblk)
{
  __shared__ bf16_t z1s[4][16][136];
  const int bid = blockIdx.x; const int c = bid / nblk; const int b = bid - c*nblk;
  hbf += (size_t)c*NHD; eg += (size_t)c*EHD; hout += (size_t)c*NHD;
  if constexpr (DOPART){ p0 += (size_t)c*NHD; p1 += (size_t)c*NHD; }
  const int tid = threadIdx.x;
  const int w = tid >> 6, l = tid & 63, r = l & 15, grp = l >> 4;
  const int rowbase = b*64 + w*16;
  const int row = rowbase + r;

  // ---- fused segment-mean (replaces k_agg) -> afr[4..7]
  bf16x8 afr[8];
  {
    int es = rowst[row], ef = rowst[row+1];
    float a0[8] = {0,0,0,0,0,0,0,0}, a1[8] = {0,0,0,0,0,0,0,0};
    float a2[8] = {0,0,0,0,0,0,0,0}, a3[8] = {0,0,0,0,0,0,0,0};
    for (int ed = es; ed < ef; ++ed){
      const bf16_t* ep = eg + (size_t)ed*HD + grp*8;
      bf16x8 v0 = *(const bf16x8*)(ep);
      bf16x8 v1 = *(const bf16x8*)(ep + 32);
      bf16x8 v2 = *(const bf16x8*)(ep + 64);
      bf16x8 v3 = *(const bf16x8*)(ep + 96);
      #pragma unroll
      for (int i = 0; i < 8; ++i){
        a0[i] += (float)v0[i]; a1[i] += (float)v1[i];
        a2[i] += (float)v2[i]; a3[i] += (float)v3[i];
      }
    }
    float sc = inv[row];
    #pragma unroll
    for (int i = 0; i < 8; ++i){
      afr[4][i] = (bf16_t)(a0[i]*sc);
      afr[5][i] = (bf16_t)(a1[i]*sc);
      afr[6][i] = (bf16_t)(a2[i]*sc);
      afr[7][i] = (bf16_t)(a3[i]*sc);
    }
  }
  #pragma unroll
  for (int kt = 0; kt < 4; ++kt)
    afr[kt] = *(const bf16x8*)(hbf + (size_t)row*HD + kt*32 + grp*8);

  #pragma unroll
  for (int nt = 0; nt < 8; ++nt){
    int cc = nt*16 + r;
    float bv = b0[cc];
    f32x4 acc = {bv, bv, bv, bv};
    #pragma unroll
    for (int kt = 0; kt < 8; ++kt){
      bf16x8 bfr = *(const bf16x8*)(W0p + ((kt*4 + grp)*HD + cc)*8);
      acc = mfma16(afr[kt], bfr, acc);
    }
    #pragma unroll
    for (int i = 0; i < 4; ++i) z1s[w][grp*4 + i][cc] = (bf16_t)elu(acc[i]);
  }
  __syncthreads();

  bf16x8 a2f[4];
  #pragma unroll
  for (int kt = 0; kt < 4; ++kt) a2f[kt] = *(const bf16x8*)&z1s[w][r][kt*32 + grp*8];
  f32x4 et[8];
  #pragma unroll
  for (int nt = 0; nt < 8; ++nt){
    int cc = nt*16 + r;
    float bv = b1[cc];
    f32x4 acc = {bv, bv, bv, bv};
    #pragma unroll
    for (int kt = 0; kt < 4; ++kt){
      bf16x8 bfr = *(const bf16x8*)(W1p + ((kt*4 + grp)*HD + cc)*8);
      acc = mfma16(a2f[kt], bfr, acc);
    }
    et[nt] = acc;
  }

  f32x4 s = {0,0,0,0}, sq = {0,0,0,0};
  #pragma unroll
  for (int nt = 0; nt < 8; ++nt){
    int cc = nt*16 + r;
    #pragma unroll
    for (int i = 0; i < 4; ++i){
      float v = et[nt][i] + hout[(size_t)(rowbase + grp*4 + i)*HD + cc];
      et[nt][i] = v; s[i] += v; sq[i] += v*v;
    }
  }
  #pragma unroll
  for (int m = 1; m < 16; m <<= 1)
    #pragma unroll
    for (int i = 0; i < 4; ++i){ s[i] += __shfl_xor(s[i], m, 64); sq[i] += __shfl_xor(sq[i], m, 64); }
  f32x4 mean, rstd;
  #pragma unroll
  for (int i = 0; i < 4; ++i){
    float mu = s[i] * (1.f/HD);
    float va = sq[i] * (1.f/HD) - mu*mu;
    mean[i] = mu; rstd[i] = rsqrtf(va + 1e-5f);
  }
  #pragma unroll
  for (int nt = 0; nt < 8; ++nt){
    int cc = nt*16 + r;
    float gv = gg[cc], bv = bb[cc];
    #pragma unroll
    for (int i = 0; i < 4; ++i){
      float o = (et[nt][i] - mean[i]) * rstd[i] * gv + bv;
      size_t oidx = (size_t)(rowbase + grp*4 + i)*HD + cc;
      bf16_t ob = (bf16_t)o;
      hout[oidx] = o;
      hbf[oidx]  = ob;
      if constexpr (DOPART) z1s[w][grp*4 + i][cc] = ob;
    }
  }

  if constexpr (DOPART){
    __builtin_amdgcn_wave_barrier();
    bf16x8 ah[4];
    #pragma unroll
    for (int kt = 0; kt < 4; ++kt) ah[kt] = *(const bf16x8*)&z1s[w][r][kt*32 + grp*8];
    #pragma unroll
    for (int nt = 0; nt < 8; ++nt){
      int cc = nt*16 + r;
      f32x4 a0 = {0,0,0,0}, a1 = {0,0,0,0};
      #pragma unroll
      for (int kt = 0; kt < 4; ++kt){
        bf16x8 bfa = *(const bf16x8*)(Wap + ((kt*4 + grp)*HD + cc)*8);
        bf16x8 bfb = *(const bf16x8*)(Wbp + ((kt*4 + grp)*HD + cc)*8);
        a0 = mfma16(ah[kt], bfa, a0);
        a1 = mfma16(ah[kt], bfb, a1);
      }
      #pragma unroll
      for (int i = 0; i < 4; ++i){
        size_t oidx = (size_t)(rowbase + grp*4 + i)*HD + cc;
        p0[oidx] = (bf16_t)a0[i];
        p1[oidx] = (bf16_t)a1[i];
      }
    }
  }
}

// ---------------------------------------------------------------- host
extern "C" void kernel_launch(void* const* d_in, const int* in_sizes, int n_in,
                              void* d_out, int out_size, void* d_ws, size_t ws_size,
                              hipStream_t stream)
{
  (void)in_sizes; (void)n_in; (void)out_size;
  const float* x         = (const float*)d_in[0];
  const float* edge_attr = (const float*)d_in[1];
  const float* mvx = (const float*)d_in[2];
  const float* svx = (const float*)d_in[3];
  const float* mve = (const float*)d_in[4];
  const float* sve = (const float*)d_in[5];
  const float* nenc_w0 = (const float*)d_in[6];
  const float* nenc_b0 = (const float*)d_in[7];
  const float* nenc_w1 = (const float*)d_in[8];
  const float* nenc_b1 = (const float*)d_in[9];
  const float* nenc_w2 = (const float*)d_in[10];
  const float* nenc_b2 = (const float*)d_in[11];
  const float* nenc_g  = (const float*)d_in[12];
  const float* nenc_be = (const float*)d_in[13];
  const float* eenc_w0 = (const float*)d_in[14];
  const float* eenc_b0 = (const float*)d_in[15];
  const float* eenc_w1 = (const float*)d_in[16];
  const float* eenc_b1 = (const float*)d_in[17];
  const float* eenc_w2 = (const float*)d_in[18];
  const float* eenc_b2 = (const float*)d_in[19];
  const float* eenc_g  = (const float*)d_in[20];
  const float* eenc_be = (const float*)d_in[21];
  const float* emp_w0 = (const float*)d_in[22];
  const float* emp_b0 = (const float*)d_in[23];
  const float* emp_w1 = (const float*)d_in[24];
  const float* emp_b1 = (const float*)d_in[25];
  const float* emp_g  = (const float*)d_in[26];
  const float* emp_be = (const float*)d_in[27];
  const float* nmp_w0 = (const float*)d_in[28];
  const float* nmp_b0 = (const float*)d_in[29];
  const float* nmp_w1 = (const float*)d_in[30];
  const float* nmp_b1 = (const float*)d_in[31];
  const float* nmp_g  = (const float*)d_in[32];
  const float* nmp_be = (const float*)d_in[33];
  const int* eidx = (const int*)d_in[34];
  const int* ei0 = eidx;
  const int* ei1 = eidx + EE;
  float* out = (float*)d_out;

  PackArgs pa;
  const float* srcs[30] = {
    eenc_w0, eenc_w1, eenc_w2, nenc_w0, nenc_w1, nenc_w2,
    emp_w0,           emp_w0 + 49152,           emp_w0 + 2*49152,           emp_w0 + 3*49152,
    emp_w0 + 16384,   emp_w0 + 49152 + 16384,   emp_w0 + 2*49152 + 16384,   emp_w0 + 3*49152 + 16384,
    emp_w0 + 32768,   emp_w0 + 49152 + 32768,   emp_w0 + 2*49152 + 32768,   emp_w0 + 3*49152 + 32768,
    emp_w1, emp_w1 + 16384, emp_w1 + 2*16384, emp_w1 + 3*16384,
    nmp_w0, nmp_w0 + 32768, nmp_w0 + 2*32768, nmp_w0 + 3*32768,
    nmp_w1, nmp_w1 + 16384, nmp_w1 + 2*16384, nmp_w1 + 3*16384 };
  const int KsA[30] = {FEE,128,128,FNN,128,128,
                       128,128,128,128, 128,128,128,128, 128,128,128,128,
                       128,128,128,128, 256,256,256,256, 128,128,128,128};
  int offs[30]; int tot = 0;
  for (int i = 0; i < 30; ++i){
    pa.j[i].src = srcs[i]; pa.j[i].K = KsA[i];
    offs[i] = tot; tot += ((KsA[i] + 31) & ~31) * HD;
  }

  const int NBn = NN/64;
  const int NBe = EE/64;
  const int NB  = (NN + 1023)/1024;

  size_t need_merged = 2*EHD*2 + 8*NHD*2 + (size_t)NN*4 + (size_t)(NN+1)*4 + 64
                     + (size_t)EE*4 + (size_t)EE*8 + (size_t)tot*2 + 1024;

  char* ws = (char*)d_ws;

  if (ws_size >= need_merged){
    // ================= MERGED PATH: both chunks per dispatch =================
    size_t off = 0;
    bf16_t* e_cur = (bf16_t*)(ws + off); off += 2*EHD*2;
    bf16_t* hbf   = (bf16_t*)(ws + off); off += 2*NHD*2;
    bf16_t* agg   = (bf16_t*)(ws + off); size_t agg_off = off; off += 2*NHD*2; (void)agg;
    bf16_t* p0    = (bf16_t*)(ws + off); off += 2*NHD*2;
    bf16_t* p1    = (bf16_t*)(ws + off); off += 2*NHD*2;
    float*  inv   = (float*)(ws + off);  off += (size_t)NN*4;
    int*    rowst = (int*)(ws + off);    off += (size_t)(NN+1)*4 + 12;
    int*    perm  = (int*)(ws + off);    off += (size_t)EE*4;
    int2*   eidx2 = (int2*)(ws + off);   off += (size_t)EE*8;
    bf16_t* wpk   = (bf16_t*)(ws + off);
    int*    cnt_i = (int*)(ws + agg_off);
    int*    curs  = (int*)(ws + agg_off + (size_t)NN*4);
    int*    incl  = (int*)(ws + agg_off + (size_t)2*NN*4);
    int*    bsum  = (int*)(ws + agg_off + (size_t)3*NN*4);
    int*    boff  = (int*)(ws + agg_off + (size_t)3*NN*4 + 256);

    hipMemsetAsync(cnt_i, 0, NN*sizeof(int), stream);
    k_cnt<<<(EE + 255)/256, 256, 0, stream>>>(ei1, cnt_i);
    k_scanA<<<NB, 1024, 0, stream>>>(cnt_i, incl, bsum);
    k_scanB<<<1, 64, 0, stream>>>(bsum, boff, NB);
    k_scanC<<<NB, 1024, 0, stream>>>(cnt_i, incl, boff, rowst, curs, inv);
    k_fill<<<(EE + 255)/256, 256, 0, stream>>>(ei0, ei1, curs, perm, eidx2);
    k_pack<<<(tot + 255)/256, 256, 0, stream>>>(pa, wpk);

    k_encoder<FEE,false,false><<<NBe, 256, 0, stream>>>(edge_attr, mve, sve,
        eenc_w0, eenc_b0, wpk + offs[1], eenc_b1, wpk + offs[2], eenc_b2,
        eenc_g, eenc_be, nullptr, e_cur, e_cur + EHD, perm, NBe,
        nullptr, nullptr, nullptr, nullptr);
    // node encoder + step-0 partials fused
    k_encoder<FNN,true,true><<<2*NBn, 256, 0, stream>>>(x, mvx, svx,
        nenc_w0, nenc_b0, wpk + offs[4], nenc_b1, wpk + offs[5], nenc_b2,
        nenc_g, nenc_be, out, hbf, nullptr, nullptr, NBn,
        wpk + offs[6], wpk + offs[10], p0, p1);

    for (int s = 0; s < SS; ++s){
      k_edge_mlp<<<2*NBe, 256, 0, stream>>>(p0, p1, e_cur, e_cur,
          wpk + offs[14+s], emp_b0 + s*HD, wpk + offs[18+s], emp_b1 + s*HD,
          emp_g + s*HD, emp_be + s*HD, eidx2, NBe);
      if (s < SS-1){
        k_node_mlp<true><<<2*NBn, 256, 0, stream>>>(hbf, e_cur, rowst, inv,
            wpk + offs[22+s], nmp_b0 + s*HD, wpk + offs[26+s], nmp_b1 + s*HD,
            nmp_g + s*HD, nmp_be + s*HD, out,
            wpk + offs[6+(s+1)], wpk + offs[10+(s+1)], p0, p1, NBn);
      } else {
        k_node_mlp<false><<<2*NBn, 256, 0, stream>>>(hbf, e_cur, rowst, inv,
            wpk + offs[22+s], nmp_b0 + s*HD, wpk + offs[26+s], nmp_b1 + s*HD,
            nmp_g + s*HD, nmp_be + s*HD, out,
            nullptr, nullptr, nullptr, nullptr, NBn);
      }
    }
  } else {
    // ================= FALLBACK (sequential chunks) =================
    size_t off = 0;
    bf16_t* e_cur = (bf16_t*)(ws + off); off += EHD*2;
    bf16_t* e0    = (bf16_t*)(ws + off); off += EHD*2;
    bf16_t* hbf   = (bf16_t*)(ws + off); off += NHD*2;
    bf16_t* agg   = (bf16_t*)(ws + off); size_t agg_off = off; off += NHD*2; (void)agg;
    bf16_t* p0    = (bf16_t*)(ws + off); off += NHD*2;
    bf16_t* p1    = (bf16_t*)(ws + off); off += NHD*2;
    float*  inv   = (float*)(ws + off);  off += (size_t)NN*4;
    int*    rowst = (int*)(ws + off);    off += (size_t)(NN+1)*4 + 12;
    int*    perm  = (int*)(ws + off);    off += (size_t)EE*4;
    int2*   eidx2 = (int2*)(ws + off);   off += (size_t)EE*8;
    bf16_t* wpk   = (bf16_t*)(ws + off);
    int*    cnt_i = (int*)(ws + agg_off);
    int*    curs  = (int*)(ws + agg_off + (size_t)NN*4);
    int*    incl  = (int*)(ws + agg_off + (size_t)2*NN*4);
    int*    bsum  = (int*)(ws + agg_off + (size_t)3*NN*4);
    int*    boff  = (int*)(ws + agg_off + (size_t)3*NN*4 + 256);

    hipMemsetAsync(cnt_i, 0, NN*sizeof(int), stream);
    k_cnt<<<(EE + 255)/256, 256, 0, stream>>>(ei1, cnt_i);
    k_scanA<<<NB, 1024, 0, stream>>>(cnt_i, incl, bsum);
    k_scanB<<<1, 64, 0, stream>>>(bsum, boff, NB);
    k_scanC<<<NB, 1024, 0, stream>>>(cnt_i, incl, boff, rowst, curs, inv);
    k_fill<<<(EE + 255)/256, 256, 0, stream>>>(ei0, ei1, curs, perm, eidx2);
    k_pack<<<(tot + 255)/256, 256, 0, stream>>>(pa, wpk);

    k_encoder<FEE,false,false><<<NBe, 256, 0, stream>>>(edge_attr, mve, sve,
        eenc_w0, eenc_b0, wpk + offs[1], eenc_b1, wpk + offs[2], eenc_b2,
        eenc_g, eenc_be, nullptr, e0, nullptr, perm, NBe,
        nullptr, nullptr, nullptr, nullptr);

    for (int c = 0; c < 2; ++c){
      float* hout = out + (size_t)c*NHD;
      k_encoder<FNN,true,true><<<NBn, 256, 0, stream>>>(x + (size_t)c*NN*FNN, mvx, svx,
          nenc_w0, nenc_b0, wpk + offs[4], nenc_b1, wpk + offs[5], nenc_b2,
          nenc_g, nenc_be, hout, hbf, nullptr, nullptr, NBn,
          wpk + offs[6], wpk + offs[10], p0, p1);
      for (int s = 0; s < SS; ++s){
        const bf16_t* e_in = (s == 0) ? e0 : e_cur;
        k_edge_mlp<<<NBe, 256, 0, stream>>>(p0, p1, e_in, e_cur,
            wpk + offs[14+s], emp_b0 + s*HD, wpk + offs[18+s], emp_b1 + s*HD,
            emp_g + s*HD, emp_be + s*HD, eidx2, NBe);
        if (s < SS-1){
          k_node_mlp<true><<<NBn, 256, 0, stream>>>(hbf, e_cur, rowst, inv,
              wpk + offs[22+s], nmp_b0 + s*HD, wpk + offs[26+s], nmp_b1 + s*HD,
              nmp_g + s*HD, nmp_be + s*HD, hout,
              wpk + offs[6+(s+1)], wpk + offs[10+(s+1)], p0, p1, NBn);
        } else {
          k_node_mlp<false><<<NBn, 256, 0, stream>>>(hbf, e_cur, rowst, inv,
              wpk + offs[22+s], nmp_b0 + s*HD, wpk + offs[26+s], nmp_b1 + s*HD,
              nmp_g + s*HD, nmp_be + s*HD, hout,
              nullptr, nullptr, nullptr, nullptr, NBn);
        }
      }
    }
  }
}